// Round 5
// baseline (1309.107 us; speedup 1.0000x reference)
//
#include <hip/hip_runtime.h>
#include <stdint.h>
#include <stddef.h>

#define M_SZ 8192
#define F_DIM 512
#define N_Q 32768

typedef __attribute__((ext_vector_type(4))) float f32x4;
typedef __attribute__((ext_vector_type(8))) __bf16 bf16x8;
typedef __attribute__((ext_vector_type(2))) __bf16 bf16x2;

__device__ __forceinline__ float bits_to_f(unsigned u) {
    union { unsigned u; float f; } v; v.u = u; return v.f;
}
// Pack two floats to bf16 pair (RNE, native cvt). Low 16 = a.
__device__ __forceinline__ unsigned pk_bf16(float a, float b) {
    union { bf16x2 v; unsigned u; } cv;
    cv.v.x = (__bf16)a; cv.v.y = (__bf16)b;
    return cv.u;
}
__device__ __forceinline__ unsigned short f2bf(float x) {
    union { bf16x2 v; unsigned u; } cv;
    cv.v.x = (__bf16)x; cv.v.y = (__bf16)0.0f;
    return (unsigned short)(cv.u & 0xffffu);
}
__device__ __forceinline__ bf16x8 as_bf16x8(uint4 u) {
    union { uint4 a; bf16x8 b; } cv; cv.a = u; return cv.b;
}

// ---------------------------------------------------------------------------
// Kernel 1: row-normalize positions & embeddings; pad to float4.
// ---------------------------------------------------------------------------
__global__ void prep_kernel(const float* __restrict__ pos,
                            const float* __restrict__ emb,
                            float* __restrict__ pn4,
                            float* __restrict__ en4,
                            float* __restrict__ pos4) {
    int i = blockIdx.x * 256 + threadIdx.x;
    if (i >= M_SZ) return;
    float x = pos[i * 3 + 0], y = pos[i * 3 + 1], z = pos[i * 3 + 2];
    float inv = 1.0f / __builtin_amdgcn_sqrtf(x * x + y * y + z * z);
    pn4[i * 4 + 0] = x * inv; pn4[i * 4 + 1] = y * inv;
    pn4[i * 4 + 2] = z * inv; pn4[i * 4 + 3] = 0.0f;
    pos4[i * 4 + 0] = x; pos4[i * 4 + 1] = y;
    pos4[i * 4 + 2] = z; pos4[i * 4 + 3] = 0.0f;
    float ex = emb[i * 3 + 0], ey = emb[i * 3 + 1], ez = emb[i * 3 + 2];
    float einv = 1.0f / __builtin_amdgcn_sqrtf(ex * ex + ey * ey + ez * ez);
    en4[i * 4 + 0] = ex * einv; en4[i * 4 + 1] = ey * einv;
    en4[i * 4 + 2] = ez * einv; en4[i * 4 + 3] = 0.0f;
}

// ---------------------------------------------------------------------------
// Kernel 2: features [8192,512] fp32 -> featT [512,8192] bf16.
// ---------------------------------------------------------------------------
__global__ void transpose_kernel(const float* __restrict__ feat,
                                 unsigned short* __restrict__ featT) {
    __shared__ float tile[64 * 65];
    const int jb = blockIdx.x * 64, fb = blockIdx.y * 64;
    const int t = threadIdx.x;
#pragma unroll
    for (int p = 0; p < 16; ++p) {
        int idx = p * 256 + t;
        int j = idx >> 6, f = idx & 63;
        tile[j * 65 + f] = feat[(size_t)(jb + j) * F_DIM + fb + f];
    }
    __syncthreads();
#pragma unroll
    for (int p = 0; p < 16; ++p) {
        int idx = p * 256 + t;
        int f = idx >> 6, j = idx & 63;
        featT[(size_t)(fb + f) * M_SZ + jb + j] = f2bf(tile[j * 65 + f]);
    }
}

// ---------------------------------------------------------------------------
// Kernel 3: fused softmax(pn@en^T) @ [features | positions] -> memT, npe4.
// BM=32, BN=512, BK=128 -> 64 iters (4x fewer barrier drains than R4).
// 512 threads, 256 blocks (1/CU). V prefetched one iter ahead in regs
// (32 uint4); P double-buffered in LDS; ONE barrier per iter.
// ---------------------------------------------------------------------------
__launch_bounds__(512, 2)
__global__ void build_memory_kernel(const float* __restrict__ pn4,
                                    const float* __restrict__ en4,
                                    const float* __restrict__ pos4,
                                    const unsigned short* __restrict__ featT,
                                    unsigned short* __restrict__ memT,
                                    float* __restrict__ npe4) {
    constexpr int BM = 32, BK = 128, PSTR = BK + 8;  // 136 shorts = 272 B
    __shared__ unsigned short pbuf[2][BM * PSTR];    // 2 x 8704 B
    __shared__ f32x4 red4[512];
    __shared__ float lbuf[BM];

    const int t = threadIdx.x;
    const int lane = t & 63, wv = t >> 6;
    const int col = lane & 15, quad = lane >> 4;
    const int mb = blockIdx.x * BM;
    const int r = t & 31, jq = t >> 5;  // P-row, j-group (8 j's each, 16 groups)

    const f32x4 pnr = ((const f32x4*)pn4)[mb + r];
    const f32x4* en = (const f32x4*)en4;
    const f32x4* ps = (const f32x4*)pos4;

    const unsigned short* bp[4];
#pragma unroll
    for (int n = 0; n < 4; ++n)
        bp[n] = featT + (size_t)(wv * 64 + n * 16 + col) * M_SZ + quad * 8;

    f32x4 acc[2][4];
    const f32x4 zero4 = {0.f, 0.f, 0.f, 0.f};
#pragma unroll
    for (int m = 0; m < 2; ++m)
#pragma unroll
        for (int n = 0; n < 4; ++n) acc[m][n] = zero4;
    float nx = 0.f, ny = 0.f, nz = 0.f, lp = 0.f;

    uint4 vbA[4][4], vbB[4][4];  // [kstep][n]
#pragma unroll
    for (int ks = 0; ks < 4; ++ks)
#pragma unroll
        for (int n = 0; n < 4; ++n)
            vbA[ks][n] = *(const uint4*)(bp[n] + ks * 32);

#define B_GEN_P(JB, SIDE)                                                    \
    {                                                                        \
        unsigned pk4[4];                                                     \
        _Pragma("unroll") for (int i = 0; i < 8; i += 2) {                   \
            int j = (JB) + jq * 8 + i;                                       \
            f32x4 e0 = en[j], e1 = en[j + 1];                                \
            f32x4 p0 = ps[j], p1 = ps[j + 1];                                \
            float s0 = fmaf(pnr.x, e0.x, fmaf(pnr.y, e0.y, pnr.z * e0.z));   \
            float s1 = fmaf(pnr.x, e1.x, fmaf(pnr.y, e1.y, pnr.z * e1.z));   \
            float w0 = __builtin_amdgcn_exp2f(s0 * 1.44269504f);             \
            float w1 = __builtin_amdgcn_exp2f(s1 * 1.44269504f);             \
            unsigned u = pk_bf16(w0, w1);                                    \
            float w0r = bits_to_f(u << 16), w1r = bits_to_f(u & 0xffff0000u);\
            lp += w0r + w1r;                                                 \
            nx = fmaf(w0r, p0.x, fmaf(w1r, p1.x, nx));                       \
            ny = fmaf(w0r, p0.y, fmaf(w1r, p1.y, ny));                       \
            nz = fmaf(w0r, p0.z, fmaf(w1r, p1.z, nz));                       \
            pk4[i >> 1] = u;                                                 \
        }                                                                    \
        *(uint4*)(&pbuf[SIDE][r * PSTR + jq * 8]) =                          \
            make_uint4(pk4[0], pk4[1], pk4[2], pk4[3]);                      \
    }

#define B_MFMA(VB, SIDE)                                                     \
    {                                                                        \
        _Pragma("unroll") for (int ks = 0; ks < 4; ++ks) {                   \
            _Pragma("unroll") for (int m = 0; m < 2; ++m) {                  \
                bf16x8 a = *(const bf16x8*)(                                 \
                    &pbuf[SIDE][(m * 16 + col) * PSTR + ks * 32 + quad * 8]);\
                _Pragma("unroll") for (int n = 0; n < 4; ++n)                \
                    acc[m][n] = __builtin_amdgcn_mfma_f32_16x16x32_bf16(     \
                        a, as_bf16x8(VB[ks][n]), acc[m][n], 0, 0, 0);        \
            }                                                                \
        }                                                                    \
    }

#define B_BODY(CUR, NXT, SIDE, JNXT)                                         \
    {                                                                        \
        _Pragma("unroll") for (int ks = 0; ks < 4; ++ks)                     \
            _Pragma("unroll") for (int n = 0; n < 4; ++n)                    \
                NXT[ks][n] = *(const uint4*)(bp[n] + BK + ks * 32);          \
        _Pragma("unroll") for (int n = 0; n < 4; ++n) bp[n] += BK;           \
        B_GEN_P(JNXT, SIDE ^ 1)                                              \
        B_MFMA(CUR, SIDE)                                                    \
        __syncthreads();                                                     \
    }

    B_GEN_P(0, 0)
    __syncthreads();

    int jn = BK;
    for (int kt = 0; kt < 62; kt += 2) {
        B_BODY(vbA, vbB, 0, jn) jn += BK;
        B_BODY(vbB, vbA, 1, jn) jn += BK;
    }
    B_BODY(vbA, vbB, 0, jn)   // iter 62: prefetch V(63), P(63)->pbuf[1]
    B_MFMA(vbB, 1)            // iter 63
#undef B_BODY
#undef B_MFMA
#undef B_GEN_P

    f32x4 mine = {nx, ny, nz, lp};
    red4[t] = mine;
    __syncthreads();
    if (t < BM) {
        f32x4 s = red4[t];
#pragma unroll
        for (int g = 1; g < 16; ++g) {
            f32x4 o = red4[t + 32 * g];
            s.x += o.x; s.y += o.y; s.z += o.z; s.w += o.w;
        }
        lbuf[t] = s.w;
        float inv = 1.0f / s.w;
        float X = s.x * inv, Y = s.y * inv, Z = s.z * inv;
        f32x4 o = {X, Y, Z, X * X + Y * Y + Z * Z};
        ((f32x4*)npe4)[mb + t] = o;
    }
    __syncthreads();

    // memT[f][m] = acc/l (C layout: col=lane&15, row=quad*4+reg)
#pragma unroll
    for (int m = 0; m < 2; ++m) {
        f32x4 l4 = *(const f32x4*)(lbuf + m * 16 + quad * 4);
        f32x4 inv4 = {1.0f / l4.x, 1.0f / l4.y, 1.0f / l4.z, 1.0f / l4.w};
        int mg = mb + m * 16 + quad * 4;
#pragma unroll
        for (int n = 0; n < 4; ++n) {
            int fg = wv * 64 + n * 16 + col;
            uint2 o;
            o.x = pk_bf16(acc[m][n].x * inv4.x, acc[m][n].y * inv4.y);
            o.y = pk_bf16(acc[m][n].z * inv4.z, acc[m][n].w * inv4.w);
            *(uint2*)(memT + (size_t)fg * M_SZ + mg) = o;
        }
    }
}

// ---------------------------------------------------------------------------
// Kernel 4: fused softmax(-cdist(q, npe)) @ memory.
// BM=64 queries, BN=256 (f split over 2 y-blocks; P computed twice — VALU
// headroom exists), BK=64 -> 128 iters. 256 threads, grid (512,2)=1024
// blocks -> 2 resident blocks/CU that desync across barrier drains.
// V prefetch one iter ahead in regs (16 uint4); P double-buffered; 1 barrier.
// ---------------------------------------------------------------------------
__launch_bounds__(256, 2)
__global__ void query_kernel(const float* __restrict__ qpos,
                             const float* __restrict__ npe4,
                             const unsigned short* __restrict__ memT,
                             float* __restrict__ out) {
    constexpr int BM = 64, BK = 64, PSTR = BK + 8;  // 72 shorts = 144 B
    __shared__ unsigned short pbuf[2][BM * PSTR];   // 2 x 9216 B
    __shared__ float redl[256];
    __shared__ float lbuf[BM];

    const int t = threadIdx.x;
    const int lane = t & 63, wv = t >> 6;           // 4 waves
    const int col = lane & 15, quad = lane >> 4;
    const int qb = blockIdx.x * BM, fb = blockIdx.y * 256;
    const int r = t & 63, jq = t >> 6;              // P-row, j-group (16 each)

    const float qx = qpos[(size_t)(qb + r) * 3 + 0];
    const float qy = qpos[(size_t)(qb + r) * 3 + 1];
    const float qz = qpos[(size_t)(qb + r) * 3 + 2];
    const float q2 = qx * qx + qy * qy + qz * qz;
    const float m2x = -2.0f * qx, m2y = -2.0f * qy, m2z = -2.0f * qz;

    const f32x4* nsrc = (const f32x4*)npe4;

    const unsigned short* bp[4];
#pragma unroll
    for (int n = 0; n < 4; ++n)
        bp[n] = memT + (size_t)(fb + wv * 64 + n * 16 + col) * M_SZ + quad * 8;

    f32x4 acc[4][4];
    const f32x4 zero4 = {0.f, 0.f, 0.f, 0.f};
#pragma unroll
    for (int m = 0; m < 4; ++m)
#pragma unroll
        for (int n = 0; n < 4; ++n) acc[m][n] = zero4;
    float lp = 0.f;

    uint4 vbA[2][4], vbB[2][4];  // [kstep][n]
#pragma unroll
    for (int ks = 0; ks < 2; ++ks)
#pragma unroll
        for (int n = 0; n < 4; ++n)
            vbA[ks][n] = *(const uint4*)(bp[n] + ks * 32);

#define Q_GEN_P(JB, SIDE)                                                    \
    {                                                                        \
        unsigned pk8[8];                                                     \
        _Pragma("unroll") for (int i = 0; i < 16; i += 2) {                  \
            int j = (JB) + jq * 16 + i;                                      \
            f32x4 n0 = nsrc[j], n1 = nsrc[j + 1];                            \
            float s0 = fmaf(m2x, n0.x, fmaf(m2y, n0.y, fmaf(m2z, n0.z, q2 + n0.w))); \
            float s1 = fmaf(m2x, n1.x, fmaf(m2y, n1.y, fmaf(m2z, n1.z, q2 + n1.w))); \
            s0 = fmaxf(s0, 1e-12f); s1 = fmaxf(s1, 1e-12f);                  \
            float w0 = __builtin_amdgcn_exp2f(__builtin_amdgcn_sqrtf(s0) * -1.44269504f); \
            float w1 = __builtin_amdgcn_exp2f(__builtin_amdgcn_sqrtf(s1) * -1.44269504f); \
            unsigned u = pk_bf16(w0, w1);                                    \
            lp += bits_to_f(u << 16) + bits_to_f(u & 0xffff0000u);           \
            pk8[i >> 1] = u;                                                 \
        }                                                                    \
        uint4* pd = (uint4*)(&pbuf[SIDE][r * PSTR + jq * 16]);               \
        pd[0] = make_uint4(pk8[0], pk8[1], pk8[2], pk8[3]);                  \
        pd[1] = make_uint4(pk8[4], pk8[5], pk8[6], pk8[7]);                  \
    }

#define Q_MFMA(VB, SIDE)                                                     \
    {                                                                        \
        _Pragma("unroll") for (int ks = 0; ks < 2; ++ks) {                   \
            _Pragma("unroll") for (int m = 0; m < 4; ++m) {                  \
                bf16x8 a = *(const bf16x8*)(                                 \
                    &pbuf[SIDE][(m * 16 + col) * PSTR + ks * 32 + quad * 8]);\
                _Pragma("unroll") for (int n = 0; n < 4; ++n)                \
                    acc[m][n] = __builtin_amdgcn_mfma_f32_16x16x32_bf16(     \
                        a, as_bf16x8(VB[ks][n]), acc[m][n], 0, 0, 0);        \
            }                                                                \
        }                                                                    \
    }

#define Q_BODY(CUR, NXT, SIDE, JNXT)                                         \
    {                                                                        \
        _Pragma("unroll") for (int ks = 0; ks < 2; ++ks)                     \
            _Pragma("unroll") for (int n = 0; n < 4; ++n)                    \
                NXT[ks][n] = *(const uint4*)(bp[n] + BK + ks * 32);          \
        _Pragma("unroll") for (int n = 0; n < 4; ++n) bp[n] += BK;           \
        Q_GEN_P(JNXT, SIDE ^ 1)                                              \
        Q_MFMA(CUR, SIDE)                                                    \
        __syncthreads();                                                     \
    }

    Q_GEN_P(0, 0)
    __syncthreads();

    int jn = BK;
    for (int kt = 0; kt < 126; kt += 2) {
        Q_BODY(vbA, vbB, 0, jn) jn += BK;
        Q_BODY(vbB, vbA, 1, jn) jn += BK;
    }
    Q_BODY(vbA, vbB, 0, jn)   // iter 126
    Q_MFMA(vbB, 1)            // iter 127
#undef Q_BODY
#undef Q_MFMA
#undef Q_GEN_P

    redl[t] = lp;
    __syncthreads();
    if (t < BM) lbuf[t] = redl[t] + redl[t + 64] + redl[t + 128] + redl[t + 192];
    __syncthreads();

#pragma unroll
    for (int m = 0; m < 4; ++m) {
        f32x4 l4 = *(const f32x4*)(lbuf + m * 16 + quad * 4);
        f32x4 inv4 = {1.0f / l4.x, 1.0f / l4.y, 1.0f / l4.z, 1.0f / l4.w};
        int qg = qb + m * 16 + quad * 4;
#pragma unroll
        for (int n = 0; n < 4; ++n) {
            int fg = fb + wv * 64 + n * 16 + col;
            out[(size_t)(qg + 0) * F_DIM + fg] = acc[m][n].x * inv4.x;
            out[(size_t)(qg + 1) * F_DIM + fg] = acc[m][n].y * inv4.y;
            out[(size_t)(qg + 2) * F_DIM + fg] = acc[m][n].z * inv4.z;
            out[(size_t)(qg + 3) * F_DIM + fg] = acc[m][n].w * inv4.w;
        }
    }
}

// ---------------------------------------------------------------------------
// Workspace layout (bytes):
//   featT : [0,        8388608)   512x8192 bf16
//   memT  : [8388608, 16777216)   512x8192 bf16
//   npe4  : [16777216,16908288)   8192x4 fp32 (x,y,z,|npe|^2)
//   pn4   : [16908288,17039360)
//   en4   : [17039360,17170432)
//   pos4  : [17170432,17301504)
// ---------------------------------------------------------------------------
extern "C" void kernel_launch(void* const* d_in, const int* in_sizes, int n_in,
                              void* d_out, int out_size, void* d_ws, size_t ws_size,
                              hipStream_t stream) {
    const float* features  = (const float*)d_in[0];
    const float* positions = (const float*)d_in[1];
    const float* qpos      = (const float*)d_in[2];
    const float* pemb      = (const float*)d_in[3];
    float* out = (float*)d_out;
    char* ws = (char*)d_ws;

    unsigned short* featT = (unsigned short*)(ws);
    unsigned short* memT  = (unsigned short*)(ws + 8388608);
    float* npe4 = (float*)(ws + 16777216);
    float* pn4  = (float*)(ws + 16908288);
    float* en4  = (float*)(ws + 17039360);
    float* pos4 = (float*)(ws + 17170432);

    hipLaunchKernelGGL(prep_kernel, dim3(M_SZ / 256), dim3(256), 0, stream,
                       positions, pemb, pn4, en4, pos4);
    hipLaunchKernelGGL(transpose_kernel, dim3(M_SZ / 64, F_DIM / 64), dim3(256), 0, stream,
                       features, featT);
    hipLaunchKernelGGL(build_memory_kernel, dim3(M_SZ / 32), dim3(512), 0, stream,
                       pn4, en4, pos4, featT, memT, npe4);
    hipLaunchKernelGGL(query_kernel, dim3(N_Q / 64, 2), dim3(256), 0, stream,
                       qpos, npe4, memT, out);
}

// Round 6
// 1015.963 us; speedup vs baseline: 1.2885x; 1.2885x over previous
//
#include <hip/hip_runtime.h>
#include <stdint.h>
#include <stddef.h>

#define M_SZ 8192
#define F_DIM 512
#define N_Q 32768

typedef __attribute__((ext_vector_type(4))) float f32x4;
typedef __attribute__((ext_vector_type(8))) __bf16 bf16x8;
typedef __attribute__((ext_vector_type(2))) __bf16 bf16x2;

__device__ __forceinline__ float bits_to_f(unsigned u) {
    union { unsigned u; float f; } v; v.u = u; return v.f;
}
// Pack two floats to bf16 pair (RNE, native cvt). Low 16 = a.
__device__ __forceinline__ unsigned pk_bf16(float a, float b) {
    union { bf16x2 v; unsigned u; } cv;
    cv.v.x = (__bf16)a; cv.v.y = (__bf16)b;
    return cv.u;
}
__device__ __forceinline__ unsigned short f2bf(float x) {
    union { bf16x2 v; unsigned u; } cv;
    cv.v.x = (__bf16)x; cv.v.y = (__bf16)0.0f;
    return (unsigned short)(cv.u & 0xffffu);
}
__device__ __forceinline__ bf16x8 as_bf16x8(uint4 u) {
    union { uint4 a; bf16x8 b; } cv; cv.a = u; return cv.b;
}

// ---------------------------------------------------------------------------
// Kernel 1: row-normalize positions & embeddings; pad to float4.
// ---------------------------------------------------------------------------
__global__ void prep_kernel(const float* __restrict__ pos,
                            const float* __restrict__ emb,
                            float* __restrict__ pn4,
                            float* __restrict__ en4,
                            float* __restrict__ pos4) {
    int i = blockIdx.x * 256 + threadIdx.x;
    if (i >= M_SZ) return;
    float x = pos[i * 3 + 0], y = pos[i * 3 + 1], z = pos[i * 3 + 2];
    float inv = 1.0f / __builtin_amdgcn_sqrtf(x * x + y * y + z * z);
    pn4[i * 4 + 0] = x * inv; pn4[i * 4 + 1] = y * inv;
    pn4[i * 4 + 2] = z * inv; pn4[i * 4 + 3] = 0.0f;
    pos4[i * 4 + 0] = x; pos4[i * 4 + 1] = y;
    pos4[i * 4 + 2] = z; pos4[i * 4 + 3] = 0.0f;
    float ex = emb[i * 3 + 0], ey = emb[i * 3 + 1], ez = emb[i * 3 + 2];
    float einv = 1.0f / __builtin_amdgcn_sqrtf(ex * ex + ey * ey + ez * ez);
    en4[i * 4 + 0] = ex * einv; en4[i * 4 + 1] = ey * einv;
    en4[i * 4 + 2] = ez * einv; en4[i * 4 + 3] = 0.0f;
}

// ---------------------------------------------------------------------------
// Kernel 2: features [8192,512] fp32 -> featT [512,8192] bf16.
// ---------------------------------------------------------------------------
__global__ void transpose_kernel(const float* __restrict__ feat,
                                 unsigned short* __restrict__ featT) {
    __shared__ float tile[64 * 65];
    const int jb = blockIdx.x * 64, fb = blockIdx.y * 64;
    const int t = threadIdx.x;
#pragma unroll
    for (int p = 0; p < 16; ++p) {
        int idx = p * 256 + t;
        int j = idx >> 6, f = idx & 63;
        tile[j * 65 + f] = feat[(size_t)(jb + j) * F_DIM + fb + f];
    }
    __syncthreads();
#pragma unroll
    for (int p = 0; p < 16; ++p) {
        int idx = p * 256 + t;
        int f = idx >> 6, j = idx & 63;
        featT[(size_t)(fb + f) * M_SZ + jb + j] = f2bf(tile[j * 65 + f]);
    }
}

// ---------------------------------------------------------------------------
// Kernel 3: fused softmax(pn@en^T) @ [features | positions] -> memT, npe4.
// BM=32, f-half 256 per block (y-split 2), BK=32. 256 threads, grid
// (256,2)=512 blocks. acc=32 AGPR -> 4 waves/SIMD, 2 blocks/CU.
// V direct global->reg per wave (its own 64 f-rows); P double-buffered LDS,
// ONE barrier/iter. lp computed fully in every block; npe written by y==0.
// ---------------------------------------------------------------------------
__launch_bounds__(256, 4)
__global__ void build_memory_kernel(const float* __restrict__ pn4,
                                    const float* __restrict__ en4,
                                    const float* __restrict__ pos4,
                                    const unsigned short* __restrict__ featT,
                                    unsigned short* __restrict__ memT,
                                    float* __restrict__ npe4) {
    constexpr int BM = 32, BK = 32, PSTR = 40;
    __shared__ unsigned short pbuf[2][BM * PSTR];  // 2 x 2560 B
    __shared__ f32x4 red4[256];
    __shared__ float lbuf[BM];

    const int t = threadIdx.x;
    const int lane = t & 63, wv = t >> 6;
    const int col = lane & 15, quad = lane >> 4;
    const int mb = blockIdx.x * BM, fb = blockIdx.y * 256;
    const bool y0 = (blockIdx.y == 0);
    const int r = t & 31, jq = t >> 5;  // P row, k-group (4 k each, 8 groups)

    const f32x4 pnr = ((const f32x4*)pn4)[mb + r];
    const f32x4* en = (const f32x4*)en4;
    const f32x4* ps = (const f32x4*)pos4;

    const unsigned short* bp0 = featT + (size_t)(fb + wv * 64 + 0 + col) * M_SZ + quad * 8;
    const unsigned short* bp1 = featT + (size_t)(fb + wv * 64 + 16 + col) * M_SZ + quad * 8;
    const unsigned short* bp2 = featT + (size_t)(fb + wv * 64 + 32 + col) * M_SZ + quad * 8;
    const unsigned short* bp3 = featT + (size_t)(fb + wv * 64 + 48 + col) * M_SZ + quad * 8;

    f32x4 acc[2][4];
    const f32x4 zero4 = {0.f, 0.f, 0.f, 0.f};
#pragma unroll
    for (int m = 0; m < 2; ++m)
#pragma unroll
        for (int n = 0; n < 4; ++n) acc[m][n] = zero4;
    float nx = 0.f, ny = 0.f, nz = 0.f, lp = 0.f;

#define B_GEN(JB, SIDE)                                                      \
    {                                                                        \
        int j = (JB) + jq * 4;                                               \
        f32x4 e0 = en[j], e1 = en[j + 1], e2 = en[j + 2], e3 = en[j + 3];    \
        float s0 = fmaf(pnr.x, e0.x, fmaf(pnr.y, e0.y, pnr.z * e0.z));       \
        float s1 = fmaf(pnr.x, e1.x, fmaf(pnr.y, e1.y, pnr.z * e1.z));       \
        float s2 = fmaf(pnr.x, e2.x, fmaf(pnr.y, e2.y, pnr.z * e2.z));       \
        float s3 = fmaf(pnr.x, e3.x, fmaf(pnr.y, e3.y, pnr.z * e3.z));       \
        unsigned u0 = pk_bf16(__builtin_amdgcn_exp2f(s0 * 1.44269504f),      \
                              __builtin_amdgcn_exp2f(s1 * 1.44269504f));     \
        unsigned u1 = pk_bf16(__builtin_amdgcn_exp2f(s2 * 1.44269504f),      \
                              __builtin_amdgcn_exp2f(s3 * 1.44269504f));     \
        float w0 = bits_to_f(u0 << 16), w1 = bits_to_f(u0 & 0xffff0000u);    \
        float w2 = bits_to_f(u1 << 16), w3 = bits_to_f(u1 & 0xffff0000u);    \
        lp += (w0 + w1) + (w2 + w3);                                         \
        if (y0) {                                                            \
            f32x4 p0 = ps[j], p1 = ps[j + 1], p2 = ps[j + 2], p3 = ps[j + 3];\
            nx += fmaf(w0, p0.x, w1 * p1.x) + fmaf(w2, p2.x, w3 * p3.x);     \
            ny += fmaf(w0, p0.y, w1 * p1.y) + fmaf(w2, p2.y, w3 * p3.y);     \
            nz += fmaf(w0, p0.z, w1 * p1.z) + fmaf(w2, p2.z, w3 * p3.z);     \
        }                                                                    \
        *(uint2*)(&pbuf[SIDE][r * PSTR + jq * 4]) = make_uint2(u0, u1);      \
    }

#define B_STEP(SIDE, DOGEN, DOSYNC, JB)                                      \
    {                                                                        \
        uint4 vb0 = *(const uint4*)bp0; bp0 += BK;                           \
        uint4 vb1 = *(const uint4*)bp1; bp1 += BK;                           \
        uint4 vb2 = *(const uint4*)bp2; bp2 += BK;                           \
        uint4 vb3 = *(const uint4*)bp3; bp3 += BK;                           \
        if (DOGEN) B_GEN(JB, (SIDE) ^ 1)                                     \
        _Pragma("unroll") for (int m = 0; m < 2; ++m) {                      \
            bf16x8 a = *(const bf16x8*)(&pbuf[SIDE][(m * 16 + col) * PSTR + quad * 8]); \
            acc[m][0] = __builtin_amdgcn_mfma_f32_16x16x32_bf16(a, as_bf16x8(vb0), acc[m][0], 0, 0, 0); \
            acc[m][1] = __builtin_amdgcn_mfma_f32_16x16x32_bf16(a, as_bf16x8(vb1), acc[m][1], 0, 0, 0); \
            acc[m][2] = __builtin_amdgcn_mfma_f32_16x16x32_bf16(a, as_bf16x8(vb2), acc[m][2], 0, 0, 0); \
            acc[m][3] = __builtin_amdgcn_mfma_f32_16x16x32_bf16(a, as_bf16x8(vb3), acc[m][3], 0, 0, 0); \
        }                                                                    \
        if (DOSYNC) __syncthreads();                                         \
    }

    B_GEN(0, 0)
    __syncthreads();

    int jn = BK;
    for (int i2 = 0; i2 < 127; ++i2) {
        B_STEP(0, true, true, jn) jn += BK;
        B_STEP(1, true, true, jn) jn += BK;
    }
    B_STEP(0, true, true, jn)   // tile 254; gen tile 255 -> side 1
    B_STEP(1, false, false, 0)  // tile 255
#undef B_STEP
#undef B_GEN

    f32x4 mine = {nx, ny, nz, lp};
    red4[t] = mine;
    __syncthreads();
    if (t < BM) {
        f32x4 s = red4[t];
#pragma unroll
        for (int g = 1; g < 8; ++g) {
            f32x4 o = red4[t + 32 * g];
            s.x += o.x; s.y += o.y; s.z += o.z; s.w += o.w;
        }
        lbuf[t] = s.w;
        if (y0) {
            float inv = 1.0f / s.w;
            float X = s.x * inv, Y = s.y * inv, Z = s.z * inv;
            f32x4 o = {X, Y, Z, X * X + Y * Y + Z * Z};
            ((f32x4*)npe4)[mb + t] = o;
        }
    }
    __syncthreads();

    // memT[f][m] = acc/l (C layout: col=lane&15 is f, row=quad*4+reg is m)
#pragma unroll
    for (int m = 0; m < 2; ++m) {
        f32x4 l4 = *(const f32x4*)(lbuf + m * 16 + quad * 4);
        f32x4 inv4 = {1.0f / l4.x, 1.0f / l4.y, 1.0f / l4.z, 1.0f / l4.w};
        int mg = mb + m * 16 + quad * 4;
#pragma unroll
        for (int n = 0; n < 4; ++n) {
            int fg = fb + wv * 64 + n * 16 + col;
            uint2 o;
            o.x = pk_bf16(acc[m][n].x * inv4.x, acc[m][n].y * inv4.y);
            o.y = pk_bf16(acc[m][n].z * inv4.z, acc[m][n].w * inv4.w);
            *(uint2*)(memT + (size_t)fg * M_SZ + mg) = o;
        }
    }
}

// ---------------------------------------------------------------------------
// Kernel 4: fused softmax(-cdist(q, npe)) @ memory.
// BM=64, full F=512, BK=32. 512 threads, grid 512 blocks. acc=64 AGPR,
// __launch_bounds__(512,4) -> 4 waves/SIMD, 2 x 512-thr blocks/CU.
// V direct global->reg per wave (disjoint 64 f-rows, no vbuf); P-tile
// computed once (4 elems/thread), double-buffered LDS; ONE barrier/iter.
// ---------------------------------------------------------------------------
__launch_bounds__(512, 4)
__global__ void query_kernel(const float* __restrict__ qpos,
                             const float* __restrict__ npe4,
                             const unsigned short* __restrict__ memT,
                             float* __restrict__ out) {
    constexpr int BM = 64, BK = 32, PSTR = 40;
    __shared__ unsigned short pbuf[2][BM * PSTR];  // 2 x 5120 B
    __shared__ float redl[512];
    __shared__ float lbuf[BM];

    const int t = threadIdx.x;
    const int lane = t & 63, wv = t >> 6;
    const int col = lane & 15, quad = lane >> 4;
    const int qb = blockIdx.x * BM;
    const int r = t & 63, jq = t >> 6;  // P row, k-group (4 k each, 8 groups)

    const float qx = qpos[(size_t)(qb + r) * 3 + 0];
    const float qy = qpos[(size_t)(qb + r) * 3 + 1];
    const float qz = qpos[(size_t)(qb + r) * 3 + 2];
    const float q2 = qx * qx + qy * qy + qz * qz;
    const float m2x = -2.0f * qx, m2y = -2.0f * qy, m2z = -2.0f * qz;

    const f32x4* nsrc = (const f32x4*)npe4;

    const unsigned short* bp0 = memT + (size_t)(wv * 64 + 0 + col) * M_SZ + quad * 8;
    const unsigned short* bp1 = memT + (size_t)(wv * 64 + 16 + col) * M_SZ + quad * 8;
    const unsigned short* bp2 = memT + (size_t)(wv * 64 + 32 + col) * M_SZ + quad * 8;
    const unsigned short* bp3 = memT + (size_t)(wv * 64 + 48 + col) * M_SZ + quad * 8;

    f32x4 acc[4][4];
    const f32x4 zero4 = {0.f, 0.f, 0.f, 0.f};
#pragma unroll
    for (int m = 0; m < 4; ++m)
#pragma unroll
        for (int n = 0; n < 4; ++n) acc[m][n] = zero4;
    float lp = 0.f;

#define Q_GEN(JB, SIDE)                                                      \
    {                                                                        \
        int j = (JB) + jq * 4;                                               \
        f32x4 n0 = nsrc[j], n1 = nsrc[j + 1], n2 = nsrc[j + 2], n3 = nsrc[j + 3]; \
        float s0 = fmaf(m2x, n0.x, fmaf(m2y, n0.y, fmaf(m2z, n0.z, q2 + n0.w))); \
        float s1 = fmaf(m2x, n1.x, fmaf(m2y, n1.y, fmaf(m2z, n1.z, q2 + n1.w))); \
        float s2 = fmaf(m2x, n2.x, fmaf(m2y, n2.y, fmaf(m2z, n2.z, q2 + n2.w))); \
        float s3 = fmaf(m2x, n3.x, fmaf(m2y, n3.y, fmaf(m2z, n3.z, q2 + n3.w))); \
        s0 = fmaxf(s0, 1e-12f); s1 = fmaxf(s1, 1e-12f);                      \
        s2 = fmaxf(s2, 1e-12f); s3 = fmaxf(s3, 1e-12f);                      \
        float w0 = __builtin_amdgcn_exp2f(__builtin_amdgcn_sqrtf(s0) * -1.44269504f); \
        float w1 = __builtin_amdgcn_exp2f(__builtin_amdgcn_sqrtf(s1) * -1.44269504f); \
        float w2 = __builtin_amdgcn_exp2f(__builtin_amdgcn_sqrtf(s2) * -1.44269504f); \
        float w3 = __builtin_amdgcn_exp2f(__builtin_amdgcn_sqrtf(s3) * -1.44269504f); \
        unsigned u0 = pk_bf16(w0, w1);                                       \
        unsigned u1 = pk_bf16(w2, w3);                                       \
        lp += (bits_to_f(u0 << 16) + bits_to_f(u0 & 0xffff0000u)) +          \
              (bits_to_f(u1 << 16) + bits_to_f(u1 & 0xffff0000u));           \
        *(uint2*)(&pbuf[SIDE][r * PSTR + jq * 4]) = make_uint2(u0, u1);      \
    }

#define Q_STEP(SIDE, DOGEN, DOSYNC, JB)                                      \
    {                                                                        \
        uint4 vb0 = *(const uint4*)bp0; bp0 += BK;                           \
        uint4 vb1 = *(const uint4*)bp1; bp1 += BK;                           \
        uint4 vb2 = *(const uint4*)bp2; bp2 += BK;                           \
        uint4 vb3 = *(const uint4*)bp3; bp3 += BK;                           \
        if (DOGEN) Q_GEN(JB, (SIDE) ^ 1)                                     \
        _Pragma("unroll") for (int m = 0; m < 4; ++m) {                      \
            bf16x8 a = *(const bf16x8*)(&pbuf[SIDE][(m * 16 + col) * PSTR + quad * 8]); \
            acc[m][0] = __builtin_amdgcn_mfma_f32_16x16x32_bf16(a, as_bf16x8(vb0), acc[m][0], 0, 0, 0); \
            acc[m][1] = __builtin_amdgcn_mfma_f32_16x16x32_bf16(a, as_bf16x8(vb1), acc[m][1], 0, 0, 0); \
            acc[m][2] = __builtin_amdgcn_mfma_f32_16x16x32_bf16(a, as_bf16x8(vb2), acc[m][2], 0, 0, 0); \
            acc[m][3] = __builtin_amdgcn_mfma_f32_16x16x32_bf16(a, as_bf16x8(vb3), acc[m][3], 0, 0, 0); \
        }                                                                    \
        if (DOSYNC) __syncthreads();                                         \
    }

    Q_GEN(0, 0)
    __syncthreads();

    int jn = BK;
    for (int i2 = 0; i2 < 127; ++i2) {
        Q_STEP(0, true, true, jn) jn += BK;
        Q_STEP(1, true, true, jn) jn += BK;
    }
    Q_STEP(0, true, true, jn)   // tile 254; gen tile 255 -> side 1
    Q_STEP(1, false, false, 0)  // tile 255
#undef Q_STEP
#undef Q_GEN

    redl[t] = lp;
    __syncthreads();
    if (t < BM) {
        float s = redl[t];
#pragma unroll
        for (int g = 1; g < 8; ++g) s += redl[t + 64 * g];
        lbuf[t] = s;
    }
    __syncthreads();

#pragma unroll
    for (int m = 0; m < 4; ++m) {
        f32x4 l4 = *(const f32x4*)(lbuf + m * 16 + quad * 4);
        f32x4 inv4 = {1.0f / l4.x, 1.0f / l4.y, 1.0f / l4.z, 1.0f / l4.w};
        int qg = qb + m * 16 + quad * 4;
#pragma unroll
        for (int n = 0; n < 4; ++n) {
            int fg = wv * 64 + n * 16 + col;
            out[(size_t)(qg + 0) * F_DIM + fg] = acc[m][n].x * inv4.x;
            out[(size_t)(qg + 1) * F_DIM + fg] = acc[m][n].y * inv4.y;
            out[(size_t)(qg + 2) * F_DIM + fg] = acc[m][n].z * inv4.z;
            out[(size_t)(qg + 3) * F_DIM + fg] = acc[m][n].w * inv4.w;
        }
    }
}

// ---------------------------------------------------------------------------
// Workspace layout (bytes):
//   featT : [0,        8388608)   512x8192 bf16
//   memT  : [8388608, 16777216)   512x8192 bf16
//   npe4  : [16777216,16908288)   8192x4 fp32 (x,y,z,|npe|^2)
//   pn4   : [16908288,17039360)
//   en4   : [17039360,17170432)
//   pos4  : [17170432,17301504)
// ---------------------------------------------------------------------------
extern "C" void kernel_launch(void* const* d_in, const int* in_sizes, int n_in,
                              void* d_out, int out_size, void* d_ws, size_t ws_size,
                              hipStream_t stream) {
    const float* features  = (const float*)d_in[0];
    const float* positions = (const float*)d_in[1];
    const float* qpos      = (const float*)d_in[2];
    const float* pemb      = (const float*)d_in[3];
    float* out = (float*)d_out;
    char* ws = (char*)d_ws;

    unsigned short* featT = (unsigned short*)(ws);
    unsigned short* memT  = (unsigned short*)(ws + 8388608);
    float* npe4 = (float*)(ws + 16777216);
    float* pn4  = (float*)(ws + 16908288);
    float* en4  = (float*)(ws + 17039360);
    float* pos4 = (float*)(ws + 17170432);

    hipLaunchKernelGGL(prep_kernel, dim3(M_SZ / 256), dim3(256), 0, stream,
                       positions, pemb, pn4, en4, pos4);
    hipLaunchKernelGGL(transpose_kernel, dim3(M_SZ / 64, F_DIM / 64), dim3(256), 0, stream,
                       features, featT);
    hipLaunchKernelGGL(build_memory_kernel, dim3(M_SZ / 32, 2), dim3(256), 0, stream,
                       pn4, en4, pos4, featT, memT, npe4);
    hipLaunchKernelGGL(query_kernel, dim3(N_Q / 64), dim3(512), 0, stream,
                       qpos, npe4, memT, out);
}